// Round 9
// baseline (247.682 us; speedup 1.0000x reference)
//
#include <hip/hip_runtime.h>

namespace {

constexpr int B = 4;
constexpr int M = 128;
constexpr int ITP = 10;
constexpr int P = M * ITP;            // 1280 queries per batch
constexpr int NPTS = 20000;
constexpr int NQ = B * P;             // 5120 queries
constexpr int QPW = 4;                // queries per wave (state ~24 regs: no spill)
constexpr int WPB = 4;                // waves per block -> 16 queries/block
constexpr int QPB = QPW * WPB;        // 16
constexpr int NCHUNKS = 8;
constexpr int CHUNK = NPTS / NCHUNKS; // 2500
constexpr int GX = NQ / QPB;          // 320 query-group blocks in x
constexpr int FULL_ITERS = CHUNK / 64;            // 39
constexpr int TAIL = CHUNK - FULL_ITERS * 64;     // 4
constexpr int C4 = CHUNK * 3 / 4;     // 1875 float4 per chunk (30000 B)
constexpr float EPSF = 0.01f;
// grid = 320 x 8 = 2560 blocks; LDS ~31KB -> 5 blocks/CU -> exactly 2 rounds.

// t = linspace(0,1,10): nearest-f32 of j/9
__device__ const float T_TAB[ITP] = {0.0f,
    (float)(1.0 / 9.0), (float)(2.0 / 9.0), (float)(3.0 / 9.0),
    (float)(4.0 / 9.0), (float)(5.0 / 9.0), (float)(6.0 / 9.0),
    (float)(7.0 / 9.0), (float)(8.0 / 9.0), 1.0f};

// Interpolated cage point, replicating reference rounding (mul,mul,add; no fma)
__device__ __forceinline__ void query_point(const float* __restrict__ cage,
                                            int b, int p,
                                            float& x, float& y, float& z) {
  const int m = p / ITP;
  const int j = p - m * ITP;
  const float t = T_TAB[j];
  const float omt = __fsub_rn(1.0f, t);
  const float* c0 = cage + ((size_t)b * M + m) * 3;
  const float* c1 = cage + ((size_t)b * M + ((m + 1) & (M - 1))) * 3;
  x = __fadd_rn(__fmul_rn(t, c1[0]), __fmul_rn(omt, c0[0]));
  y = __fadd_rn(__fmul_rn(t, c1[1]), __fmul_rn(omt, c0[1]));
  z = __fadd_rn(__fmul_rn(t, c1[2]), __fmul_rn(omt, c0[2]));
}

// Fused kernel: grid (GX=320, NCHUNKS=8), 256 threads.
// Phase 1: LDS-stage chunk, register-resident (QPW=4, no-spill) argmin scan.
// Phase 2 (8th-arrival block per group): merge chunk partials in chunk order,
//          compute the group's 16 losses, fixed-order tree -> gsum[bx].
// Phase 3 (320th group completion): fixed-order sum of gsum -> mean.
__global__ __launch_bounds__(256) void k_fused(
    const float* __restrict__ cage,
    const float* __restrict__ shape,
    const float* __restrict__ normals,
    unsigned long long* __restrict__ part,
    unsigned int* __restrict__ ticket_x,   // [GX], zeroed per call
    unsigned int* __restrict__ tick2,      // [1], zeroed per call
    float* __restrict__ gsum,              // [GX]
    float* __restrict__ out) {
  __shared__ float4 smem4[C4];             // 30000 B chunk stage
  __shared__ float red[256];
  __shared__ unsigned int flag;

  const int tid  = threadIdx.x;
  const int lane = tid & 63;
  const int wid  = tid >> 6;
  const int bx   = blockIdx.x;             // query group (16 queries)
  const int ck   = blockIdx.y;             // chunk
  const int q0   = bx * QPB + wid * QPW;
  const int b    = (bx * QPB) / P;         // uniform per block (16 | 1280)
  const int p0   = q0 - b * P;

  // ---- stage chunk into LDS (float4 x 1875) ----
  const float4* g4 = reinterpret_cast<const float4*>(shape + (size_t)b * NPTS * 3)
                     + (size_t)ck * C4;
  for (int i = tid; i < C4; i += 256) smem4[i] = g4[i];

  // ---- per-wave query setup (overlaps staging latency) ----
  float cx[QPW], cy[QPW], cz[QPW], cc[QPW];
#pragma unroll
  for (int i = 0; i < QPW; ++i) {
    float x, y, z;
    query_point(cage, b, p0 + i, x, y, z);
    cx[i] = x; cy[i] = y; cz[i] = z;
    cc[i] = __fadd_rn(__fadd_rn(__fmul_rn(x, x), __fmul_rn(y, y)), __fmul_rn(z, z));
  }
  float minv[QPW];
  unsigned int mini[QPW];
#pragma unroll
  for (int i = 0; i < QPW; ++i) { minv[i] = __int_as_float(0x7f800000); mini[i] = 0u; }

  __syncthreads();
  const float* sm = reinterpret_cast<const float*>(smem4);
  const int nbase = ck * CHUNK;

  // ---- scan: full unroll -> one LDS base + immediate offsets (39*768 < 64K),
  //      pure VALU+DS, state fully register-resident ----
#pragma unroll
  for (int it = 0; it < FULL_ITERS; ++it) {
    const int j = it * 64 + lane;
    const float px = sm[3 * j], py = sm[3 * j + 1], pz = sm[3 * j + 2];
    const float ss = __fadd_rn(__fadd_rn(__fmul_rn(px, px), __fmul_rn(py, py)),
                               __fmul_rn(pz, pz));
    const int n = nbase + j;
#pragma unroll
    for (int i = 0; i < QPW; ++i) {
      const float dot = __fmaf_rn(cz[i], pz, __fmaf_rn(cy[i], py, __fmul_rn(cx[i], px)));
      const float d2 = __fmaf_rn(-2.0f, dot, __fadd_rn(cc[i], ss));
      if (d2 < minv[i]) { minv[i] = d2; mini[i] = (unsigned int)n; }  // strict <: first idx
    }
  }
  {  // tail: 4 valid lanes; others read in-bounds dummy and mask via +inf
    const int j = (lane < TAIL) ? (FULL_ITERS * 64 + lane) : lane;
    const float px = sm[3 * j], py = sm[3 * j + 1], pz = sm[3 * j + 2];
    float ss = __fadd_rn(__fadd_rn(__fmul_rn(px, px), __fmul_rn(py, py)),
                         __fmul_rn(pz, pz));
    if (lane >= TAIL) ss = __int_as_float(0x7f800000);
    const int n = nbase + j;
#pragma unroll
    for (int i = 0; i < QPW; ++i) {
      const float dot = __fmaf_rn(cz[i], pz, __fmaf_rn(cy[i], py, __fmul_rn(cx[i], px)));
      const float d2 = __fmaf_rn(-2.0f, dot, __fadd_rn(cc[i], ss));
      if (d2 < minv[i]) { minv[i] = d2; mini[i] = (unsigned int)n; }
    }
  }

  // ---- per-wave argmin reduce, write packed partials ----
#pragma unroll
  for (int i = 0; i < QPW; ++i) {
    unsigned int fb = __float_as_uint(minv[i]);
    fb = (fb & 0x80000000u) ? ~fb : (fb | 0x80000000u);  // monotone total order
    unsigned long long pk = ((unsigned long long)fb << 32) | (unsigned long long)mini[i];
#pragma unroll
    for (int s = 32; s >= 1; s >>= 1) {
      const unsigned long long o = __shfl_xor(pk, s, 64);
      pk = (o < pk) ? o : pk;   // equal d2 -> smaller idx (first-index tie-break)
    }
    if (lane == i) part[(size_t)(q0 + i) * NCHUNKS + ck] = pk;
  }

  // ---- group ticket: 8th arrival (tickets zeroed per call) merges ----
  __syncthreads();                 // all waves' partial stores issued
  __threadfence();                 // release: partials visible device-wide
  if (tid == 0) {
    const unsigned int o = atomicAdd(&ticket_x[bx], 1u);
    flag = (o == 7u) ? 1u : 0u;    // provably the last of the 8 chunk-blocks
  }
  __syncthreads();
  if (!flag) return;
  __threadfence();                 // acquire: see other blocks' partials

  // ---- phase 2: merge + loss for this group's 16 queries (first 2 waves) ----
  if (tid < 8 * QPB) {             // 128 threads
    const int ql = tid >> 3;       // 0..15 query-local
    const int c  = tid & 7;        // 0..7 chunk
    unsigned long long v = part[(size_t)(bx * QPB + ql) * NCHUNKS + c];
#pragma unroll
    for (int s = 1; s < 8; s <<= 1) {  // min over aligned 8-lane subgroup
      const unsigned long long o = __shfl_xor(v, s, 64);
      v = (o < v) ? o : v;
    }
    if (c == 0) {
      const int idx = (int)(v & 0xffffffffu);
      const int q = bx * QPB + ql;
      const int p = q - b * P;
      float qx, qy, qz;
      query_point(cage, b, p, qx, qy, qz);
      const float* sp = shape   + ((size_t)b * NPTS + idx) * 3;
      const float* sn = normals + ((size_t)b * NPTS + idx) * 3;
      const float nx = sn[0], ny = sn[1], nz = sn[2];
      const float vx = __fsub_rn(__fsub_rn(qx, sp[0]), __fmul_rn(EPSF, nx));
      const float vy = __fsub_rn(__fsub_rn(qy, sp[1]), __fmul_rn(EPSF, ny));
      const float vz = __fsub_rn(__fsub_rn(qz, sp[2]), __fmul_rn(EPSF, nz));
      const float dot = __fadd_rn(__fadd_rn(__fmul_rn(vx, nx), __fmul_rn(vy, ny)),
                                  __fmul_rn(vz, nz));
      red[ql] = (dot < 0.0f) ? -dot : 0.0f;   // red[0..15]
    }
  }
  __syncthreads();
#pragma unroll
  for (int s = 8; s >= 1; s >>= 1) {   // fixed-order tree over 16
    if (tid < s) red[tid] = __fadd_rn(red[tid], red[tid + s]);
    __syncthreads();
  }
  if (tid == 0) gsum[bx] = red[0];

  // ---- global ticket: 320th group completion sums all group sums ----
  __threadfence();                 // release gsum
  if (tid == 0) {
    const unsigned int o = atomicAdd(tick2, 1u);
    flag = (o == (unsigned)(GX - 1)) ? 1u : 0u;
  }
  __syncthreads();
  if (!flag) return;
  __threadfence();                 // acquire gsum

  // 320 entries: fold [256..319] into [0..63], then tree over 256 (fixed order)
  red[tid] = __fadd_rn(gsum[tid], (tid < GX - 256) ? gsum[256 + tid] : 0.0f);
  __syncthreads();
#pragma unroll
  for (int s = 128; s >= 1; s >>= 1) {
    if (tid < s) red[tid] = __fadd_rn(red[tid], red[tid + s]);
    __syncthreads();
  }
  if (tid == 0) out[0] = red[0] / (float)NQ;
}

}  // namespace

extern "C" void kernel_launch(void* const* d_in, const int* in_sizes, int n_in,
                              void* d_out, int out_size, void* d_ws, size_t ws_size,
                              hipStream_t stream) {
  (void)in_sizes; (void)n_in; (void)out_size; (void)ws_size;
  const float* cage    = (const float*)d_in[0];
  const float* shape   = (const float*)d_in[1];
  const float* normals = (const float*)d_in[2];
  float* out = (float*)d_out;

  char* ws = (char*)d_ws;
  unsigned long long* part = (unsigned long long*)ws;              // 5120*8*8B = 320 KB
  unsigned int* ticket_x   = (unsigned int*)(ws + 320 * 1024);     // 320 u32
  unsigned int* tick2      = (unsigned int*)(ws + 320 * 1024 + 1280);  // 1 u32
  float* gsum              = (float*)(ws + 320 * 1024 + 2048);     // 320 f32

  // Zero tickets each call -> winners are provably the LAST arrivals.
  hipMemsetAsync(ws + 320 * 1024, 0, 2048, stream);

  dim3 grid(GX, NCHUNKS);   // 320 x 8 = 2560 blocks = exactly 2 rounds at 5/CU
  k_fused<<<grid, 256, 0, stream>>>(cage, shape, normals, part, ticket_x, tick2,
                                    gsum, out);
}

// Round 11
// 33.824 us; speedup vs baseline: 7.3226x; 7.3226x over previous
//
#include <hip/hip_runtime.h>

namespace {

constexpr int B = 4;
constexpr int M = 128;
constexpr int ITP = 10;
constexpr int P = M * ITP;            // 1280 queries per batch
constexpr int NPTS = 20000;
constexpr int NQ = B * P;             // 5120 queries
constexpr int QPW = 8;                // queries per wave
constexpr int WPB = 4;                // waves per block -> 32 queries/block
constexpr int QPB = QPW * WPB;        // 32
constexpr int NCHUNKS = 8;
constexpr int CHUNK = NPTS / NCHUNKS; // 2500
constexpr int GX = NQ / QPB;          // 160 blocks in x; grid 160x8=1280 (5/CU)
constexpr int FULL_ITERS = CHUNK / 64;            // 39
constexpr int TAIL = CHUNK - FULL_ITERS * 64;     // 4
constexpr int C4 = CHUNK * 3 / 4;     // 1875 float4 per chunk (30000 B)
constexpr float EPSF = 0.01f;

// t = linspace(0,1,10): nearest-f32 of j/9
__device__ const float T_TAB[ITP] = {0.0f,
    (float)(1.0 / 9.0), (float)(2.0 / 9.0), (float)(3.0 / 9.0),
    (float)(4.0 / 9.0), (float)(5.0 / 9.0), (float)(6.0 / 9.0),
    (float)(7.0 / 9.0), (float)(8.0 / 9.0), 1.0f};

// Interpolated cage point, replicating reference rounding (mul,mul,add; no fma)
__device__ __forceinline__ void query_point(const float* __restrict__ cage,
                                            int b, int p,
                                            float& x, float& y, float& z) {
  const int m = p / ITP;
  const int j = p - m * ITP;
  const float t = T_TAB[j];
  const float omt = __fsub_rn(1.0f, t);
  const float* c0 = cage + ((size_t)b * M + m) * 3;
  const float* c1 = cage + ((size_t)b * M + ((m + 1) & (M - 1))) * 3;
  x = __fadd_rn(__fmul_rn(t, c1[0]), __fmul_rn(omt, c0[0]));
  y = __fadd_rn(__fmul_rn(t, c1[1]), __fmul_rn(omt, c0[1]));
  z = __fadd_rn(__fmul_rn(t, c1[2]), __fmul_rn(omt, c0[2]));
}

// Kernel 1: LDS-staged argmin scan. NO fences, NO tickets — kernel boundary
// provides ordering. grid (GX=160, NCHUNKS=8), 256 threads, LDS 30KB.
__global__ __launch_bounds__(256) void k_nn_lds(
    const float* __restrict__ cage,
    const float* __restrict__ shape,
    unsigned long long* __restrict__ part) {
  __shared__ float4 smem4[C4];            // 30000 B chunk stage

  const int tid  = threadIdx.x;
  const int lane = tid & 63;
  const int wid  = tid >> 6;
  const int bx   = blockIdx.x;            // query group (32 queries)
  const int ck   = blockIdx.y;            // chunk
  const int q0   = bx * QPB + wid * QPW;
  const int b    = (bx * QPB) / P;        // uniform per block (32 | 1280)
  const int p0   = q0 - b * P;

  // ---- stage chunk into LDS (float4 x 1875) ----
  const float4* g4 = reinterpret_cast<const float4*>(shape + (size_t)b * NPTS * 3)
                     + (size_t)ck * C4;
  for (int i = tid; i < C4; i += 256) smem4[i] = g4[i];

  // ---- per-wave query setup (overlaps staging latency) ----
  float cx[QPW], cy[QPW], cz[QPW], cc[QPW];
#pragma unroll
  for (int i = 0; i < QPW; ++i) {
    float x, y, z;
    query_point(cage, b, p0 + i, x, y, z);
    cx[i] = x; cy[i] = y; cz[i] = z;
    cc[i] = __fadd_rn(__fadd_rn(__fmul_rn(x, x), __fmul_rn(y, y)), __fmul_rn(z, z));
  }
  float minv[QPW];
  unsigned int mini[QPW];
#pragma unroll
  for (int i = 0; i < QPW; ++i) { minv[i] = __int_as_float(0x7f800000); mini[i] = 0u; }

  __syncthreads();
  const float* sm = reinterpret_cast<const float*>(smem4);
  const int nbase = ck * CHUNK;

  // ---- scan loop: pure VALU + LDS (AoS, 12B stride: banks 3-apart, no conflict) ----
#pragma unroll 4
  for (int it = 0; it < FULL_ITERS; ++it) {
    const int j = it * 64 + lane;
    const float px = sm[3 * j], py = sm[3 * j + 1], pz = sm[3 * j + 2];
    const float ss = __fadd_rn(__fadd_rn(__fmul_rn(px, px), __fmul_rn(py, py)),
                               __fmul_rn(pz, pz));
    const int n = nbase + j;
#pragma unroll
    for (int i = 0; i < QPW; ++i) {
      const float dot = __fmaf_rn(cz[i], pz, __fmaf_rn(cy[i], py, __fmul_rn(cx[i], px)));
      const float d2 = __fmaf_rn(-2.0f, dot, __fadd_rn(cc[i], ss));
      if (d2 < minv[i]) { minv[i] = d2; mini[i] = (unsigned int)n; }  // strict <: first idx
    }
  }
  {  // tail: 4 valid lanes; others read in-bounds dummy and mask via +inf
    const int j = (lane < TAIL) ? (FULL_ITERS * 64 + lane) : lane;
    const float px = sm[3 * j], py = sm[3 * j + 1], pz = sm[3 * j + 2];
    float ss = __fadd_rn(__fadd_rn(__fmul_rn(px, px), __fmul_rn(py, py)),
                         __fmul_rn(pz, pz));
    if (lane >= TAIL) ss = __int_as_float(0x7f800000);
    const int n = nbase + j;
#pragma unroll
    for (int i = 0; i < QPW; ++i) {
      const float dot = __fmaf_rn(cz[i], pz, __fmaf_rn(cy[i], py, __fmul_rn(cx[i], px)));
      const float d2 = __fmaf_rn(-2.0f, dot, __fadd_rn(cc[i], ss));
      if (d2 < minv[i]) { minv[i] = d2; mini[i] = (unsigned int)n; }
    }
  }

  // ---- per-wave argmin reduce, write packed partials ----
#pragma unroll
  for (int i = 0; i < QPW; ++i) {
    unsigned int fb = __float_as_uint(minv[i]);
    fb = (fb & 0x80000000u) ? ~fb : (fb | 0x80000000u);  // monotone total order
    unsigned long long pk = ((unsigned long long)fb << 32) | (unsigned long long)mini[i];
#pragma unroll
    for (int s = 32; s >= 1; s >>= 1) {
      const unsigned long long o = __shfl_xor(pk, s, 64);
      pk = (o < pk) ? o : pk;   // equal d2 -> smaller idx (first-index tie-break)
    }
    if (lane == i) part[(size_t)(q0 + i) * NCHUNKS + ck] = pk;
  }
}

// Kernel 2: one thread per query: merge chunk partials (chunk-index order),
// compute loss term, fixed-order block tree-reduce -> per-block sum.
__global__ __launch_bounds__(256) void k_loss(
    const float* __restrict__ cage,
    const float* __restrict__ shape,
    const float* __restrict__ normals,
    const unsigned long long* __restrict__ part,
    float* __restrict__ blocksum) {
  const int tid = threadIdx.x;
  const int q = blockIdx.x * 256 + tid;   // NQ = 20 blocks * 256

  unsigned long long best = ~0ull;
#pragma unroll
  for (int c = 0; c < NCHUNKS; ++c) {
    const unsigned long long v = part[(size_t)q * NCHUNKS + c];
    if (v < best) best = v;   // strict < in ascending chunk order keeps first index
  }
  const int idx = (int)(best & 0xffffffffu);
  const int b = q / P;
  const int p = q - b * P;
  float qx, qy, qz;
  query_point(cage, b, p, qx, qy, qz);
  const float* sp = shape   + ((size_t)b * NPTS + idx) * 3;
  const float* sn = normals + ((size_t)b * NPTS + idx) * 3;
  const float nx = sn[0], ny = sn[1], nz = sn[2];
  const float vx = __fsub_rn(__fsub_rn(qx, sp[0]), __fmul_rn(EPSF, nx));
  const float vy = __fsub_rn(__fsub_rn(qy, sp[1]), __fmul_rn(EPSF, ny));
  const float vz = __fsub_rn(__fsub_rn(qz, sp[2]), __fmul_rn(EPSF, nz));
  const float dot = __fadd_rn(__fadd_rn(__fmul_rn(vx, nx), __fmul_rn(vy, ny)),
                              __fmul_rn(vz, nz));
  const float loss = (dot < 0.0f) ? -dot : 0.0f;

  __shared__ float red[256];
  red[tid] = loss;
  __syncthreads();
#pragma unroll
  for (int s = 128; s >= 1; s >>= 1) {
    if (tid < s) red[tid] = __fadd_rn(red[tid], red[tid + s]);
    __syncthreads();
  }
  if (tid == 0) blocksum[blockIdx.x] = red[0];
}

// Kernel 3: sum the 20 block partials (single wave, fixed butterfly order).
__global__ __launch_bounds__(64) void k_sum(const float* __restrict__ blocksum,
                                            float* __restrict__ out) {
  const int lane = threadIdx.x;
  float v = (lane < NQ / 256) ? blocksum[lane] : 0.0f;
#pragma unroll
  for (int s = 32; s >= 1; s >>= 1) v = __fadd_rn(v, __shfl_xor(v, s, 64));
  if (lane == 0) out[0] = v / (float)NQ;
}

}  // namespace

extern "C" void kernel_launch(void* const* d_in, const int* in_sizes, int n_in,
                              void* d_out, int out_size, void* d_ws, size_t ws_size,
                              hipStream_t stream) {
  (void)in_sizes; (void)n_in; (void)out_size; (void)ws_size;
  const float* cage    = (const float*)d_in[0];
  const float* shape   = (const float*)d_in[1];
  const float* normals = (const float*)d_in[2];
  float* out = (float*)d_out;

  char* ws = (char*)d_ws;
  unsigned long long* part = (unsigned long long*)ws;        // 5120*8*8B = 320 KB
  float* blocksum = (float*)(ws + 320 * 1024);               // 20 floats

  dim3 grid1(GX, NCHUNKS);   // 160 x 8 = 1280 blocks (5/CU, one round), 4 waves
  k_nn_lds<<<grid1, 256, 0, stream>>>(cage, shape, part);
  k_loss<<<NQ / 256, 256, 0, stream>>>(cage, shape, normals, part, blocksum);
  k_sum<<<1, 64, 0, stream>>>(blocksum, out);
}